// Round 1
// 885.874 us; speedup vs baseline: 1.3247x; 1.3247x over previous
//
#include <hip/hip_runtime.h>
#include <hip/hip_bf16.h>

// ---------------------------------------------------------------------------
// Gemma2 attention layer: qkv proj -> rope -> causal GQA attn (softcap) -> o proj
// T=2048 HID=3584 NH=16 NKV=8 HD=256
// R6: m97-structure GEMMs. Weights are transposed+converted to bf16 [N,K] in a
// prep pass; both GEMMs become 128x128-tile bf16 gemm_bt with
// global_load_lds width-16 staging (HW-verified ~900 TF structure).
// Attention unchanged from R5.
// ---------------------------------------------------------------------------

#define T_SEQ 2048
#define HID_DIM 3584
#define NH 16
#define NKV 8
#define HD 256
#define QKV_N ((NH + 2 * NKV) * HD)   // 8192
#define ATT_N (NH * HD)               // 4096
#define V_OFF ((NH + NKV) * HD)       // 6144

typedef __bf16 bf16_t;
typedef bf16_t bf16x8 __attribute__((ext_vector_type(8)));
typedef float f32x4 __attribute__((ext_vector_type(4)));

// async global->LDS, 16B per lane; LDS dest is wave-uniform base + lane*16
__device__ __forceinline__ void gload16(const bf16_t* g, bf16_t* l) {
  __builtin_amdgcn_global_load_lds(
      (const __attribute__((address_space(1))) unsigned int*)g,
      (__attribute__((address_space(3))) unsigned int*)l, 16, 0, 0);
}

// ---------------------------------------------------------------------------
// Prep 1: fp32 -> bf16 linear convert (hidden_states). n = grid*256*8 exactly.
// ---------------------------------------------------------------------------
__global__ __launch_bounds__(256) void convert_bf16(
    const float* __restrict__ in, bf16_t* __restrict__ out) {
  const long i = ((long)blockIdx.x * 256 + threadIdx.x) * 8;
  const float4 f0 = *(const float4*)(in + i);
  const float4 f1 = *(const float4*)(in + i + 4);
  bf16x8 v;
  v[0] = (bf16_t)f0.x; v[1] = (bf16_t)f0.y; v[2] = (bf16_t)f0.z; v[3] = (bf16_t)f0.w;
  v[4] = (bf16_t)f1.x; v[5] = (bf16_t)f1.y; v[6] = (bf16_t)f1.z; v[7] = (bf16_t)f1.w;
  *(bf16x8*)(out + i) = v;
}

// ---------------------------------------------------------------------------
// Prep 2: transpose + convert: in [K,N] fp32 -> out [N,K] bf16. 64x64 tiles,
// coalesced reads (float4) and writes (bf16x8) via LDS.
// ---------------------------------------------------------------------------
__global__ __launch_bounds__(256) void transpose_bf16(
    const float* __restrict__ in, bf16_t* __restrict__ out, int K, int N) {
  __shared__ __align__(16) bf16_t tile[64][80];  // [n][k], 160B rows (16B-aligned)
  const int k0 = blockIdx.x * 64;
  const int n0 = blockIdx.y * 64;
  const int t = threadIdx.x;
  const int rr = t >> 4;          // 0..15 (k within pass)
  const int rc = (t & 15) * 4;    // n offset
#pragma unroll
  for (int i = 0; i < 4; ++i) {
    const int k = rr + i * 16;
    const float4 v = *(const float4*)(in + (long)(k0 + k) * N + n0 + rc);
    tile[rc + 0][k] = (bf16_t)v.x;
    tile[rc + 1][k] = (bf16_t)v.y;
    tile[rc + 2][k] = (bf16_t)v.z;
    tile[rc + 3][k] = (bf16_t)v.w;
  }
  __syncthreads();
  const int wn = t >> 3;          // 0..31
  const int wk = (t & 7) * 8;     // 0..56
#pragma unroll
  for (int i = 0; i < 2; ++i) {
    const int n = wn + i * 32;
    *(bf16x8*)(out + (long)(n0 + n) * K + k0 + wk) = *(const bf16x8*)&tile[n][wk];
  }
}

// ---------------------------------------------------------------------------
// GEMM (m97 structure): C[M,N] = A[M,K] @ Bt[N,K]^T, both bf16 row-major.
// Block 256 (4 waves), tile 128x128, BK=32. Wave w -> 64x64 quadrant
// (wm=w&1, wn=w>>1), acc 4x4 of 16x16 frags. Staging: global_load_lds
// width-16 into linear As/Bs[128][32]; 2 barriers per K-step.
// Columns >= voff are written TRANSPOSED to Vt[(col-voff)*QKV_N + row].
// ---------------------------------------------------------------------------
template <typename TC>
__global__ __launch_bounds__(256) void gemm_bt(
    const bf16_t* __restrict__ A, const bf16_t* __restrict__ Bt,
    TC* __restrict__ C, bf16_t* __restrict__ Vt, int voff,
    int M, int N, int K) {
  const int n0 = blockIdx.x * 128;
  const int m0 = blockIdx.y * 128;
  const int t = threadIdx.x;
  const int w = t >> 6;
  const int lane = t & 63;
  const int l16 = lane & 15;
  const int quad = lane >> 4;

  __shared__ __align__(16) bf16_t As[128][32];  // 8KB, rows = 64B
  __shared__ __align__(16) bf16_t Bs[128][32];  // 8KB

  f32x4 acc[4][4];
#pragma unroll
  for (int i = 0; i < 4; ++i)
#pragma unroll
    for (int j = 0; j < 4; ++j) acc[i][j] = f32x4{0, 0, 0, 0};

  // staging: 16 units of (64 lanes x 16B = 1KB = 16 rows); 4 units per wave.
  // waves 0,1 -> A rows w*64..+63 ; waves 2,3 -> B rows (w-2)*64..+63
  const int srow = lane >> 2;        // row within 16-row unit
  const int scol = (lane & 3) * 8;   // elem col within BK=32
  const bf16_t* gsrc;
  bf16_t* lbase;
  if (w < 2) {
    gsrc = A + (long)(m0 + w * 64 + srow) * K + scol;
    lbase = &As[w * 64][0];
  } else {
    gsrc = Bt + (long)(n0 + (w - 2) * 64 + srow) * K + scol;
    lbase = &Bs[(w - 2) * 64][0];
  }

  const int wm = w & 1;
  const int wn = w >> 1;

  for (int k0 = 0; k0 < K; k0 += 32) {
#pragma unroll
    for (int j = 0; j < 4; ++j)
      gload16(gsrc + (long)j * 16 * K + k0, lbase + j * (16 * 32));
    __syncthreads();  // drains vmcnt(0): LDS tiles ready

    bf16x8 af[4], bfr[4];
#pragma unroll
    for (int i = 0; i < 4; ++i) {
      af[i] = *(const bf16x8*)&As[wm * 64 + i * 16 + l16][quad * 8];
      bfr[i] = *(const bf16x8*)&Bs[wn * 64 + i * 16 + l16][quad * 8];
    }
#pragma unroll
    for (int i = 0; i < 4; ++i)
#pragma unroll
      for (int j = 0; j < 4; ++j)
        acc[i][j] = __builtin_amdgcn_mfma_f32_16x16x32_bf16(af[i], bfr[j],
                                                            acc[i][j], 0, 0, 0);
    __syncthreads();  // LDS reuse
  }

  // C/D layout: col = l16, row = quad*4 + r (verified in R5)
#pragma unroll
  for (int i = 0; i < 4; ++i) {
    const int row = m0 + wm * 64 + i * 16 + quad * 4;
#pragma unroll
    for (int j = 0; j < 4; ++j) {
      const int col = n0 + wn * 64 + j * 16 + l16;
#pragma unroll
      for (int r = 0; r < 4; ++r) {
        if (col >= voff)
          Vt[(long)(col - voff) * QKV_N + (row + r)] = (bf16_t)acc[i][j][r];
        else
          C[(long)(row + r) * N + col] = (TC)acc[i][j][r];
      }
    }
  }
}

// ---------------------------------------------------------------------------
// Neox-style RoPE over full HD=256, in-place on bf16 qkv (q: 16 heads, k: 8).
// ---------------------------------------------------------------------------
__global__ void rope_kernel(const int* __restrict__ positions,
                            bf16_t* __restrict__ qkv) {
  const int head = blockIdx.x;   // 0..23 : 0..15 q heads, 16..23 k heads
  const int trow = blockIdx.y;
  const int d = threadIdx.x;     // 0..127 (pairs with d+128)
  const long col0 = (head < NH) ? (long)head * HD
                                : (long)(NH * HD) + (long)(head - NH) * HD;
  bf16_t* p = qkv + (long)trow * QKV_N + col0;
  const float pos = (float)positions[trow];
  const float inv_freq = exp2f(-(float)d * (13.287712379549449f / 128.0f));
  const float ang = pos * inv_freq;
  float s, c;
  sincosf(ang, &s, &c);
  const float x1 = (float)p[d];
  const float x2 = (float)p[d + 128];
  p[d]       = (bf16_t)(x1 * c - x2 * s);
  p[d + 128] = (bf16_t)(x2 * c + x1 * s);
}

// ---------------------------------------------------------------------------
// MFMA flash attention (unchanged from R5). Block = 256 (4 waves) = one
// (head, 32 q-rows) tile.
// ---------------------------------------------------------------------------
__global__ __launch_bounds__(256) void attn_mfma(
    const bf16_t* __restrict__ qkv, const bf16_t* __restrict__ vt,
    bf16_t* __restrict__ out /* [T, 4096] */) {
  const int h = blockIdx.x;
  const int q0 = blockIdx.y * 32;
  const int t = threadIdx.x;
  const int w = t >> 6;
  const int lane = t & 63;
  const int l16 = lane & 15;
  const int quad = lane >> 4;
  const int wq = w & 1;
  const int wk = w >> 1;
  const int kvh = h >> 1;

  __shared__ __align__(16) bf16_t Ps[32][40];
  __shared__ float pmax[2][32];
  __shared__ float ppsum[2][32];

  bf16x8 qf[8];
  {
    const bf16_t* qbase =
        qkv + (long)(q0 + wq * 16 + l16) * QKV_N + h * HD + quad * 8;
#pragma unroll
    for (int s = 0; s < 8; ++s) qf[s] = *(const bf16x8*)(qbase + s * 32);
  }

  const bf16_t* kbase =
      qkv + (long)(wk * 16 + l16) * QKV_N + NH * HD + kvh * HD + quad * 8;
  const bf16_t* vbase =
      vt + (long)(kvh * HD + wk * 128 + l16) * QKV_N + quad * 8;

  f32x4 oacc[8];
#pragma unroll
  for (int nt = 0; nt < 8; ++nt) oacc[nt] = f32x4{0, 0, 0, 0};
  float m_state[4], l_state[4];
#pragma unroll
  for (int r = 0; r < 4; ++r) { m_state[r] = -1e30f; l_state[r] = 0.0f; }

  const int ktiles = q0 / 32 + 1;
  for (int kt = 0; kt < ktiles; ++kt) {
    bf16x8 vf[8];
    {
      const bf16_t* vp = vbase + kt * 32;
#pragma unroll
      for (int nt = 0; nt < 8; ++nt)
        vf[nt] = *(const bf16x8*)(vp + (long)nt * 16 * QKV_N);
    }
    f32x4 sacc = f32x4{0, 0, 0, 0};
    {
      const bf16_t* kp = kbase + (long)kt * 32 * QKV_N;
#pragma unroll
      for (int s = 0; s < 8; ++s) {
        bf16x8 kf = *(const bf16x8*)(kp + s * 32);
        sacc = __builtin_amdgcn_mfma_f32_16x16x32_bf16(qf[s], kf, sacc, 0, 0, 0);
      }
    }

    float sv[4], rmax[4];
#pragma unroll
    for (int r = 0; r < 4; ++r) {
      const float x = sacc[r] * 0.0625f;
      const float e = __expf(x * 0.04f);
      float tz = 50.0f * (e - 1.0f) / (e + 1.0f);
      const int row = q0 + wq * 16 + quad * 4 + r;
      const int col = kt * 32 + wk * 16 + l16;
      sv[r] = (col <= row) ? tz : -1e30f;
      float rm = sv[r];
      rm = fmaxf(rm, __shfl_xor(rm, 1));
      rm = fmaxf(rm, __shfl_xor(rm, 2));
      rm = fmaxf(rm, __shfl_xor(rm, 4));
      rm = fmaxf(rm, __shfl_xor(rm, 8));
      rmax[r] = rm;
    }
    if (l16 == 0) {
#pragma unroll
      for (int r = 0; r < 4; ++r) pmax[wk][wq * 16 + quad * 4 + r] = rmax[r];
    }
    __syncthreads();

    float mnew[4], psum[4];
#pragma unroll
    for (int r = 0; r < 4; ++r) {
      const int ridx = wq * 16 + quad * 4 + r;
      const float mt = fmaxf(pmax[0][ridx], pmax[1][ridx]);
      mnew[r] = fmaxf(m_state[r], mt);
      const float p = (sv[r] > -1e29f) ? __expf(sv[r] - mnew[r]) : 0.0f;
      Ps[ridx][wk * 16 + l16] = (bf16_t)p;
      float ps = p;
      ps += __shfl_xor(ps, 1);
      ps += __shfl_xor(ps, 2);
      ps += __shfl_xor(ps, 4);
      ps += __shfl_xor(ps, 8);
      psum[r] = ps;
    }
    if (l16 == 0) {
#pragma unroll
      for (int r = 0; r < 4; ++r) ppsum[wk][wq * 16 + quad * 4 + r] = psum[r];
    }
    __syncthreads();

#pragma unroll
    for (int r = 0; r < 4; ++r) {
      const int ridx = wq * 16 + quad * 4 + r;
      const float tot = ppsum[0][ridx] + ppsum[1][ridx];
      const float alpha = __expf(m_state[r] - mnew[r]);
      l_state[r] = l_state[r] * alpha + tot;
      m_state[r] = mnew[r];
#pragma unroll
      for (int nt = 0; nt < 8; ++nt) oacc[nt][r] *= alpha;
    }

    const bf16x8 pa = *(const bf16x8*)&Ps[wq * 16 + l16][quad * 8];
#pragma unroll
    for (int nt = 0; nt < 8; ++nt)
      oacc[nt] = __builtin_amdgcn_mfma_f32_16x16x32_bf16(pa, vf[nt], oacc[nt], 0, 0, 0);
  }

#pragma unroll
  for (int r = 0; r < 4; ++r) {
    const float inv = 1.0f / l_state[r];
    const long row = q0 + wq * 16 + quad * 4 + r;
    bf16_t* op = out + row * ATT_N + h * HD + wk * 128 + l16;
#pragma unroll
    for (int nt = 0; nt < 8; ++nt) op[nt * 16] = (bf16_t)(oacc[nt][r] * inv);
  }
}

// ---------------------------------------------------------------------------
extern "C" void kernel_launch(void* const* d_in, const int* in_sizes, int n_in,
                              void* d_out, int out_size, void* d_ws, size_t ws_size,
                              hipStream_t stream) {
  const int* positions = (const int*)d_in[0];
  const float* hidden = (const float*)d_in[1];
  const float* w_qkv = (const float*)d_in[2];
  const float* w_o = (const float*)d_in[3];
  float* out = (float*)d_out;

  // workspace layout (bf16): total ~153 MB
  bf16_t* qkv = (bf16_t*)d_ws;                          // [2048, 8192]  33.6MB
  bf16_t* attn = qkv + (size_t)T_SEQ * QKV_N;           // [2048, 4096]  16.8MB
  bf16_t* hid_bf = attn + (size_t)T_SEQ * ATT_N;        // [2048, 3584]  14.7MB
  bf16_t* wqkv_t = hid_bf + (size_t)T_SEQ * HID_DIM;    // [8192, 3584]  58.7MB
  bf16_t* wo_t = wqkv_t + (size_t)QKV_N * HID_DIM;      // [3584, 4096]  29.4MB
  bf16_t* vtb = qkv + V_OFF;  // V^T lives in the V slot: vt(d,t)=vtb[d*8192+t]

  // 0) prep: bf16 convert + weight transposes
  convert_bf16<<<(T_SEQ * HID_DIM) / 2048, 256, 0, stream>>>(hidden, hid_bf);
  transpose_bf16<<<dim3(HID_DIM / 64, QKV_N / 64), 256, 0, stream>>>(
      w_qkv, wqkv_t, HID_DIM, QKV_N);
  transpose_bf16<<<dim3(ATT_N / 64, HID_DIM / 64), 256, 0, stream>>>(
      w_o, wo_t, ATT_N, HID_DIM);

  // 1) qkv = hidden @ w_qkv ; V columns routed transposed into vtb
  gemm_bt<bf16_t><<<dim3(QKV_N / 128, T_SEQ / 128), 256, 0, stream>>>(
      hid_bf, wqkv_t, qkv, vtb, V_OFF, T_SEQ, QKV_N, HID_DIM);
  // 2) rope on q,k in-place (V slot untouched)
  rope_kernel<<<dim3(NH + NKV, T_SEQ), 128, 0, stream>>>(positions, qkv);
  // 3) MFMA flash attention
  attn_mfma<<<dim3(NH, T_SEQ / 32), 256, 0, stream>>>(qkv, vtb, attn);
  // 4) out = attn @ w_o
  gemm_bt<float><<<dim3(HID_DIM / 128, T_SEQ / 128), 256, 0, stream>>>(
      attn, wo_t, out, attn /*unused*/, 1 << 30, T_SEQ, HID_DIM, ATT_N);
}

// Round 2
// 845.912 us; speedup vs baseline: 1.3873x; 1.0472x over previous
//
#include <hip/hip_runtime.h>
#include <hip/hip_bf16.h>

// ---------------------------------------------------------------------------
// Gemma2 attention layer: qkv proj -> rope -> causal GQA attn (softcap) -> o proj
// T=2048 HID=3584 NH=16 NKV=8 HD=256
// R7: barrier-free wave-independent flash attention. Each wave owns 16 q-rows
// and all 32 keys of a tile: softmax is wave-internal (shfl over 16-lane
// groups), P transpose via per-wave LDS slab, zero __syncthreads in the loop.
// Causal work paired (chunk i with 127-i) and KV heads pinned per-XCD so K/V
// stay resident in the local 4MB L2. GEMMs unchanged from R6.
// ---------------------------------------------------------------------------

#define T_SEQ 2048
#define HID_DIM 3584
#define NH 16
#define NKV 8
#define HD 256
#define QKV_N ((NH + 2 * NKV) * HD)   // 8192
#define ATT_N (NH * HD)               // 4096
#define V_OFF ((NH + NKV) * HD)       // 6144

typedef __bf16 bf16_t;
typedef bf16_t bf16x8 __attribute__((ext_vector_type(8)));
typedef float f32x4 __attribute__((ext_vector_type(4)));

// async global->LDS, 16B per lane; LDS dest is wave-uniform base + lane*16
__device__ __forceinline__ void gload16(const bf16_t* g, bf16_t* l) {
  __builtin_amdgcn_global_load_lds(
      (const __attribute__((address_space(1))) unsigned int*)g,
      (__attribute__((address_space(3))) unsigned int*)l, 16, 0, 0);
}

// ---------------------------------------------------------------------------
// Prep 1: fp32 -> bf16 linear convert (hidden_states). n = grid*256*8 exactly.
// ---------------------------------------------------------------------------
__global__ __launch_bounds__(256) void convert_bf16(
    const float* __restrict__ in, bf16_t* __restrict__ out) {
  const long i = ((long)blockIdx.x * 256 + threadIdx.x) * 8;
  const float4 f0 = *(const float4*)(in + i);
  const float4 f1 = *(const float4*)(in + i + 4);
  bf16x8 v;
  v[0] = (bf16_t)f0.x; v[1] = (bf16_t)f0.y; v[2] = (bf16_t)f0.z; v[3] = (bf16_t)f0.w;
  v[4] = (bf16_t)f1.x; v[5] = (bf16_t)f1.y; v[6] = (bf16_t)f1.z; v[7] = (bf16_t)f1.w;
  *(bf16x8*)(out + i) = v;
}

// ---------------------------------------------------------------------------
// Prep 2: transpose + convert: in [K,N] fp32 -> out [N,K] bf16. 64x64 tiles,
// coalesced reads (float4) and writes (bf16x8) via LDS.
// ---------------------------------------------------------------------------
__global__ __launch_bounds__(256) void transpose_bf16(
    const float* __restrict__ in, bf16_t* __restrict__ out, int K, int N) {
  __shared__ __align__(16) bf16_t tile[64][80];  // [n][k], 160B rows (16B-aligned)
  const int k0 = blockIdx.x * 64;
  const int n0 = blockIdx.y * 64;
  const int t = threadIdx.x;
  const int rr = t >> 4;          // 0..15 (k within pass)
  const int rc = (t & 15) * 4;    // n offset
#pragma unroll
  for (int i = 0; i < 4; ++i) {
    const int k = rr + i * 16;
    const float4 v = *(const float4*)(in + (long)(k0 + k) * N + n0 + rc);
    tile[rc + 0][k] = (bf16_t)v.x;
    tile[rc + 1][k] = (bf16_t)v.y;
    tile[rc + 2][k] = (bf16_t)v.z;
    tile[rc + 3][k] = (bf16_t)v.w;
  }
  __syncthreads();
  const int wn = t >> 3;          // 0..31
  const int wk = (t & 7) * 8;     // 0..56
#pragma unroll
  for (int i = 0; i < 2; ++i) {
    const int n = wn + i * 32;
    *(bf16x8*)(out + (long)(n0 + n) * K + k0 + wk) = *(const bf16x8*)&tile[n][wk];
  }
}

// ---------------------------------------------------------------------------
// GEMM (m97 structure): C[M,N] = A[M,K] @ Bt[N,K]^T, both bf16 row-major.
// Block 256 (4 waves), tile 128x128, BK=32. Columns >= voff are written
// TRANSPOSED to Vt[(col-voff)*QKV_N + row].
// ---------------------------------------------------------------------------
template <typename TC>
__global__ __launch_bounds__(256) void gemm_bt(
    const bf16_t* __restrict__ A, const bf16_t* __restrict__ Bt,
    TC* __restrict__ C, bf16_t* __restrict__ Vt, int voff,
    int M, int N, int K) {
  const int n0 = blockIdx.x * 128;
  const int m0 = blockIdx.y * 128;
  const int t = threadIdx.x;
  const int w = t >> 6;
  const int lane = t & 63;
  const int l16 = lane & 15;
  const int quad = lane >> 4;

  __shared__ __align__(16) bf16_t As[128][32];  // 8KB
  __shared__ __align__(16) bf16_t Bs[128][32];  // 8KB

  f32x4 acc[4][4];
#pragma unroll
  for (int i = 0; i < 4; ++i)
#pragma unroll
    for (int j = 0; j < 4; ++j) acc[i][j] = f32x4{0, 0, 0, 0};

  const int srow = lane >> 2;        // row within 16-row unit
  const int scol = (lane & 3) * 8;   // elem col within BK=32
  const bf16_t* gsrc;
  bf16_t* lbase;
  if (w < 2) {
    gsrc = A + (long)(m0 + w * 64 + srow) * K + scol;
    lbase = &As[w * 64][0];
  } else {
    gsrc = Bt + (long)(n0 + (w - 2) * 64 + srow) * K + scol;
    lbase = &Bs[(w - 2) * 64][0];
  }

  const int wm = w & 1;
  const int wn = w >> 1;

  for (int k0 = 0; k0 < K; k0 += 32) {
#pragma unroll
    for (int j = 0; j < 4; ++j)
      gload16(gsrc + (long)j * 16 * K + k0, lbase + j * (16 * 32));
    __syncthreads();

    bf16x8 af[4], bfr[4];
#pragma unroll
    for (int i = 0; i < 4; ++i) {
      af[i] = *(const bf16x8*)&As[wm * 64 + i * 16 + l16][quad * 8];
      bfr[i] = *(const bf16x8*)&Bs[wn * 64 + i * 16 + l16][quad * 8];
    }
#pragma unroll
    for (int i = 0; i < 4; ++i)
#pragma unroll
      for (int j = 0; j < 4; ++j)
        acc[i][j] = __builtin_amdgcn_mfma_f32_16x16x32_bf16(af[i], bfr[j],
                                                            acc[i][j], 0, 0, 0);
    __syncthreads();
  }

#pragma unroll
  for (int i = 0; i < 4; ++i) {
    const int row = m0 + wm * 64 + i * 16 + quad * 4;
#pragma unroll
    for (int j = 0; j < 4; ++j) {
      const int col = n0 + wn * 64 + j * 16 + l16;
#pragma unroll
      for (int r = 0; r < 4; ++r) {
        if (col >= voff)
          Vt[(long)(col - voff) * QKV_N + (row + r)] = (bf16_t)acc[i][j][r];
        else
          C[(long)(row + r) * N + col] = (TC)acc[i][j][r];
      }
    }
  }
}

// ---------------------------------------------------------------------------
// Neox-style RoPE over full HD=256, in-place on bf16 qkv (q: 16 heads, k: 8).
// ---------------------------------------------------------------------------
__global__ void rope_kernel(const int* __restrict__ positions,
                            bf16_t* __restrict__ qkv) {
  const int head = blockIdx.x;   // 0..23 : 0..15 q heads, 16..23 k heads
  const int trow = blockIdx.y;
  const int d = threadIdx.x;     // 0..127 (pairs with d+128)
  const long col0 = (head < NH) ? (long)head * HD
                                : (long)(NH * HD) + (long)(head - NH) * HD;
  bf16_t* p = qkv + (long)trow * QKV_N + col0;
  const float pos = (float)positions[trow];
  const float inv_freq = exp2f(-(float)d * (13.287712379549449f / 128.0f));
  const float ang = pos * inv_freq;
  float s, c;
  sincosf(ang, &s, &c);
  const float x1 = (float)p[d];
  const float x2 = (float)p[d + 128];
  p[d]       = (bf16_t)(x1 * c - x2 * s);
  p[d + 128] = (bf16_t)(x2 * c + x1 * s);
}

// ---------------------------------------------------------------------------
// R7 flash attention: barrier-free, wave-independent.
// Grid = 512 linear blocks x 256 threads (4 waves). Wave = one 16-row q-chunk,
// all 32 keys per tile. kvh pinned to XCD (lid&7); chunk pairing balances
// causal work within block and across co-resident blocks.
// Per tile: 16 K-frag loads -> 2x8 QK MFMA -> wave-internal softmax (softcap,
// causal, online rescale) -> P via per-wave LDS slab -> 2x(8 V loads + 8 PV
// MFMA). No __syncthreads anywhere.
// ---------------------------------------------------------------------------
__global__ __launch_bounds__(256) void attn_mfma(
    const bf16_t* __restrict__ qkv, const bf16_t* __restrict__ vt,
    bf16_t* __restrict__ out /* [T, 4096] */) {
  const int lid = blockIdx.x;        // 0..511
  const int kvh = lid & 7;           // XCD-pinned KV head (lid%8 round-robin)
  const int slot = lid >> 3;         // 0..63
  const int h = 2 * kvh + (slot & 1);
  const int ps = slot >> 1;          // 0..31
  // pb mapping: co-resident blocks (lid, lid+256) -> pb and pb' with
  // duration(pb)+duration(pb') ~ const (97 tiles)
  const int pb = (ps < 16) ? ps : 47 - ps;
  const int t = threadIdx.x;
  const int w = t >> 6;
  const int lane = t & 63;
  const int l16 = lane & 15;
  const int quad = lane >> 4;
  // waves 0,1 -> light chunks 2pb,2pb+1 ; waves 2,3 -> heavy 126-2pb,127-2pb
  const int chunk = (w < 2) ? (2 * pb + w) : (124 - 2 * pb + w);
  const int q0 = chunk * 16;
  const int ktiles = (chunk >> 1) + 1;

  __shared__ __align__(16) bf16_t Ps[4][16][40];  // per-wave P slab

  // Q A-frags: A[m=l16][k=quad*8+j], d in 8 steps of 32
  bf16x8 qf[8];
  const bf16_t* qbase = qkv + (long)(q0 + l16) * QKV_N + h * HD + quad * 8;
#pragma unroll
  for (int s = 0; s < 8; ++s) qf[s] = *(const bf16x8*)(qbase + s * 32);

  const bf16_t* kbase = qkv + (long)l16 * QKV_N + (NH * HD) + kvh * HD + quad * 8;
  const bf16_t* vbase = vt + (long)(kvh * HD + l16) * QKV_N + quad * 8;

  f32x4 oacc[16];  // O[16q][256d]: frag nt -> cols nt*16+l16
#pragma unroll
  for (int nt = 0; nt < 16; ++nt) oacc[nt] = f32x4{0, 0, 0, 0};
  float m_state[4], l_state[4];
#pragma unroll
  for (int r = 0; r < 4; ++r) { m_state[r] = -1e30f; l_state[r] = 0.0f; }

  for (int kt = 0; kt < ktiles; ++kt) {
    // K B-frags: B[n=key16][k=d], 2 key-groups x 8 d-steps, all in flight
    bf16x8 kf[2][8];
    const bf16_t* kp = kbase + (long)(kt * 32) * QKV_N;
#pragma unroll
    for (int g = 0; g < 2; ++g)
#pragma unroll
      for (int s = 0; s < 8; ++s)
        kf[g][s] = *(const bf16x8*)(kp + (long)(g * 16) * QKV_N + s * 32);

    f32x4 sacc[2] = {f32x4{0, 0, 0, 0}, f32x4{0, 0, 0, 0}};
    __builtin_amdgcn_s_setprio(1);
#pragma unroll
    for (int g = 0; g < 2; ++g)
#pragma unroll
      for (int s = 0; s < 8; ++s)
        sacc[g] = __builtin_amdgcn_mfma_f32_16x16x32_bf16(qf[s], kf[g][s],
                                                          sacc[g], 0, 0, 0);
    __builtin_amdgcn_s_setprio(0);

    // softcap + causal + wave-internal online softmax
    // C-layout: row = q0+quad*4+r, col = kt*32+g*16+l16
    float alpha[4];
#pragma unroll
    for (int r = 0; r < 4; ++r) {
      const int row = q0 + quad * 4 + r;
      float svg[2];
      float best = -1e30f;
#pragma unroll
      for (int g = 0; g < 2; ++g) {
        const float x = sacc[g][r] * 0.0625f;
        const float e = __expf(x * 0.04f);           // e^(2x/50)
        const float tz = 50.0f * (e - 1.0f) / (e + 1.0f);
        const int col = kt * 32 + g * 16 + l16;
        svg[g] = (col <= row) ? tz : -1e30f;
        best = fmaxf(best, svg[g]);
      }
      best = fmaxf(best, __shfl_xor(best, 1));
      best = fmaxf(best, __shfl_xor(best, 2));
      best = fmaxf(best, __shfl_xor(best, 4));
      best = fmaxf(best, __shfl_xor(best, 8));
      const float mnew = fmaxf(m_state[r], best);
      float psum = 0.0f;
#pragma unroll
      for (int g = 0; g < 2; ++g) {
        const float pv = (svg[g] > -1e29f) ? __expf(svg[g] - mnew) : 0.0f;
        Ps[w][quad * 4 + r][g * 16 + l16] = (bf16_t)pv;
        psum += pv;
      }
      psum += __shfl_xor(psum, 1);
      psum += __shfl_xor(psum, 2);
      psum += __shfl_xor(psum, 4);
      psum += __shfl_xor(psum, 8);
      alpha[r] = __expf(m_state[r] - mnew);
      l_state[r] = l_state[r] * alpha[r] + psum;
      m_state[r] = mnew;
    }
#pragma unroll
    for (int nt = 0; nt < 16; ++nt) {
      oacc[nt][0] *= alpha[0];
      oacc[nt][1] *= alpha[1];
      oacc[nt][2] *= alpha[2];
      oacc[nt][3] *= alpha[3];
    }

    // wave-internal transpose: C-layout writes above, A-layout read here
    // (same-wave ds ordering via lgkmcnt, no barrier needed)
    const bf16x8 pa = *(const bf16x8*)&Ps[w][l16][quad * 8];

    // PV in two d-halves to cap VGPR: B[n=d][k=key] frags from V^T
#pragma unroll
    for (int h2 = 0; h2 < 2; ++h2) {
      bf16x8 vf[8];
#pragma unroll
      for (int nt = 0; nt < 8; ++nt)
        vf[nt] = *(const bf16x8*)(vbase + (long)(h2 * 128 + nt * 16) * QKV_N +
                                  kt * 32);
      __builtin_amdgcn_s_setprio(1);
#pragma unroll
      for (int nt = 0; nt < 8; ++nt)
        oacc[h2 * 8 + nt] = __builtin_amdgcn_mfma_f32_16x16x32_bf16(
            pa, vf[nt], oacc[h2 * 8 + nt], 0, 0, 0);
      __builtin_amdgcn_s_setprio(0);
    }
  }

  // epilogue: row = q0+quad*4+r, col = h*HD + nt*16 + l16
#pragma unroll
  for (int r = 0; r < 4; ++r) {
    const float inv = 1.0f / l_state[r];
    bf16_t* op = out + (long)(q0 + quad * 4 + r) * ATT_N + h * HD + l16;
#pragma unroll
    for (int nt = 0; nt < 16; ++nt) op[nt * 16] = (bf16_t)(oacc[nt][r] * inv);
  }
}

// ---------------------------------------------------------------------------
extern "C" void kernel_launch(void* const* d_in, const int* in_sizes, int n_in,
                              void* d_out, int out_size, void* d_ws, size_t ws_size,
                              hipStream_t stream) {
  const int* positions = (const int*)d_in[0];
  const float* hidden = (const float*)d_in[1];
  const float* w_qkv = (const float*)d_in[2];
  const float* w_o = (const float*)d_in[3];
  float* out = (float*)d_out;

  // workspace layout (bf16): total ~153 MB
  bf16_t* qkv = (bf16_t*)d_ws;                          // [2048, 8192]  33.6MB
  bf16_t* attn = qkv + (size_t)T_SEQ * QKV_N;           // [2048, 4096]  16.8MB
  bf16_t* hid_bf = attn + (size_t)T_SEQ * ATT_N;        // [2048, 3584]  14.7MB
  bf16_t* wqkv_t = hid_bf + (size_t)T_SEQ * HID_DIM;    // [8192, 3584]  58.7MB
  bf16_t* wo_t = wqkv_t + (size_t)QKV_N * HID_DIM;      // [3584, 4096]  29.4MB
  bf16_t* vtb = qkv + V_OFF;  // V^T lives in the V slot: vt(d,t)=vtb[d*8192+t]

  // 0) prep: bf16 convert + weight transposes
  convert_bf16<<<(T_SEQ * HID_DIM) / 2048, 256, 0, stream>>>(hidden, hid_bf);
  transpose_bf16<<<dim3(HID_DIM / 64, QKV_N / 64), 256, 0, stream>>>(
      w_qkv, wqkv_t, HID_DIM, QKV_N);
  transpose_bf16<<<dim3(ATT_N / 64, HID_DIM / 64), 256, 0, stream>>>(
      w_o, wo_t, ATT_N, HID_DIM);

  // 1) qkv = hidden @ w_qkv ; V columns routed transposed into vtb
  gemm_bt<bf16_t><<<dim3(QKV_N / 128, T_SEQ / 128), 256, 0, stream>>>(
      hid_bf, wqkv_t, qkv, vtb, V_OFF, T_SEQ, QKV_N, HID_DIM);
  // 2) rope on q,k in-place (V slot untouched)
  rope_kernel<<<dim3(NH + NKV, T_SEQ), 128, 0, stream>>>(positions, qkv);
  // 3) barrier-free MFMA flash attention (512 linear blocks, XCD-pinned KV)
  attn_mfma<<<512, 256, 0, stream>>>(qkv, vtb, attn);
  // 4) out = attn @ w_o
  gemm_bt<float><<<dim3(HID_DIM / 128, T_SEQ / 128), 256, 0, stream>>>(
      attn, wo_t, out, attn /*unused*/, 1 << 30, T_SEQ, HID_DIM, ATT_N);
}